// Round 1
// baseline (369.442 us; speedup 1.0000x reference)
//
#include <hip/hip_runtime.h>
#include <hip/hip_bf16.h>

// B=2, S=2048, D=1024, H=16, DK=64
// Pipeline (all fp16 compute, fp32 accum):
//   1. cvt_x: x fp32 -> fp16
//   2. wt_kernel: W[k][n] fp32 -> Wt[n][k] fp16 (transposed, MFMA B-operand form)
//   3. gemm_bt<true> x3: Q/K/V = x@W + b  -> fp16 [B,S,D]
//   4. attn: flash attention (online softmax), causal -> ctx fp16 [B,S,D]
//   5. gemm_bt<false>: out = ctx@Wo + bo -> fp32
// Workspace layout (40 MiB): xh@0 (8M, reused as ctx), WqT@8M, WkT@10M,
//   WvT@12M, WoT@14M (2M each), Qh@16M, Kh@24M, Vh@32M.

typedef _Float16 f16x8 __attribute__((ext_vector_type(8)));
typedef _Float16 f16x4 __attribute__((ext_vector_type(4)));
typedef float f32x4 __attribute__((ext_vector_type(4)));

#define GM 4096
#define GN 1024
#define GK 1024

// ---------------- fp32 -> fp16 convert (x) ----------------
__global__ __launch_bounds__(256) void cvt_x(const float* __restrict__ x,
                                             _Float16* __restrict__ xh) {
  int i = (blockIdx.x * 256 + threadIdx.x) * 4;
  float4 v = *(const float4*)(x + i);
  f16x4 o;
  o.x = (_Float16)v.x; o.y = (_Float16)v.y;
  o.z = (_Float16)v.z; o.w = (_Float16)v.w;
  *(f16x4*)(xh + i) = o;
}

// ---------------- W transpose + convert ----------------
__global__ __launch_bounds__(256) void wt_kernel(
    const float* __restrict__ W0, const float* __restrict__ W1,
    const float* __restrict__ W2, const float* __restrict__ W3,
    _Float16* __restrict__ T0, _Float16* __restrict__ T1,
    _Float16* __restrict__ T2, _Float16* __restrict__ T3) {
  const float* W; _Float16* T;
  switch (blockIdx.z) {
    case 0: W = W0; T = T0; break;
    case 1: W = W1; T = T1; break;
    case 2: W = W2; T = T2; break;
    default: W = W3; T = T3; break;
  }
  __shared__ _Float16 tile[32][33];
  const int tx = threadIdx.x & 31, ty = threadIdx.x >> 5;  // ty 0..7
  const int n0 = blockIdx.x * 32, k0 = blockIdx.y * 32;
  for (int i = 0; i < 4; i++) {
    int kk = k0 + ty + i * 8;
    tile[ty + i * 8][tx] = (_Float16)W[(size_t)kk * 1024 + n0 + tx];
  }
  __syncthreads();
  for (int i = 0; i < 4; i++) {
    int nn = n0 + ty + i * 8;
    T[(size_t)nn * 1024 + k0 + tx] = tile[tx][ty + i * 8];
  }
}

// ---------------- GEMM: C[M,N] = A[M,K] @ Bt[N,K]^T + bias ----------------
// 128x128 tile, BK=32, 256 threads = 4 waves, each wave 64x64 (4x4 MFMA tiles)
template <bool BOUT>
__global__ __launch_bounds__(256) void gemm_bt(
    const _Float16* __restrict__ A, const _Float16* __restrict__ Bt,
    const float* __restrict__ bias, _Float16* __restrict__ outh,
    float* __restrict__ outf) {
  __shared__ _Float16 As[128 * 32];
  __shared__ _Float16 Bs[128 * 32];
  const int tid = threadIdx.x;
  const int wave = tid >> 6, lane = tid & 63;
  const int lr = lane & 15, lq = lane >> 4;
  const int m0 = blockIdx.x * 128, n0 = blockIdx.y * 128;
  const int rw = (wave & 1) * 64, cw = (wave >> 1) * 64;

  f32x4 acc[4][4] = {};

  const int sr = tid >> 2;         // 0..63: staging row
  const int sc = (tid & 3) * 8;    // staging col (elements)

  for (int kt = 0; kt < GK; kt += 32) {
    uint4 a0 = *(const uint4*)(A + (size_t)(m0 + sr) * GK + kt + sc);
    uint4 a1 = *(const uint4*)(A + (size_t)(m0 + 64 + sr) * GK + kt + sc);
    uint4 b0 = *(const uint4*)(Bt + (size_t)(n0 + sr) * GK + kt + sc);
    uint4 b1 = *(const uint4*)(Bt + (size_t)(n0 + 64 + sr) * GK + kt + sc);
    __syncthreads();  // previous iteration's frag reads done
    *(uint4*)(As + sr * 32 + sc) = a0;
    *(uint4*)(As + (64 + sr) * 32 + sc) = a1;
    *(uint4*)(Bs + sr * 32 + sc) = b0;
    *(uint4*)(Bs + (64 + sr) * 32 + sc) = b1;
    __syncthreads();
    f16x8 af[4], bf[4];
    for (int i = 0; i < 4; i++)
      af[i] = *(const f16x8*)(As + (rw + i * 16 + lr) * 32 + lq * 8);
    for (int j = 0; j < 4; j++)
      bf[j] = *(const f16x8*)(Bs + (cw + j * 16 + lr) * 32 + lq * 8);
    for (int i = 0; i < 4; i++)
      for (int j = 0; j < 4; j++)
        acc[i][j] = __builtin_amdgcn_mfma_f32_16x16x32_f16(af[i], bf[j],
                                                           acc[i][j], 0, 0, 0);
  }

  // epilogue: C row = (lane>>4)*4 + reg, col = lane&15  [m89/m91 layout]
  for (int i = 0; i < 4; i++) {
    const int row = m0 + rw + i * 16 + lq * 4;
    for (int j = 0; j < 4; j++) {
      const int col = n0 + cw + j * 16 + lr;
      const float bv = bias[col];
      for (int r = 0; r < 4; r++) {
        float v = acc[i][j][r] + bv;
        if (BOUT) outh[(size_t)(row + r) * GN + col] = (_Float16)v;
        else      outf[(size_t)(row + r) * GN + col] = v;
      }
    }
  }
}

// ---------------- flash attention ----------------
// grid (S/64, H, B); 256 threads = 4 waves; wave w owns q rows [q0+16w, q0+16w+16)
__global__ __launch_bounds__(256) void attn(const _Float16* __restrict__ Q,
                                            const _Float16* __restrict__ K,
                                            const _Float16* __restrict__ V,
                                            _Float16* __restrict__ ctx) {
  const int qt = blockIdx.x;           // 0..31
  const int h = blockIdx.y, b = blockIdx.z;
  const int tid = threadIdx.x, wave = tid >> 6, lane = tid & 63;
  const int lr = lane & 15, lq = lane >> 4;
  const int q0 = qt * 64;
  const size_t base = ((size_t)b * 2048) * 1024 + h * 64;

  __shared__ _Float16 Vt[64 * 72];      // Vt[dk][kv], stride 72 (144B, b128-aligned)
  __shared__ _Float16 Ps[4][16 * 72];   // per-wave P strip [row][kv]

  // Q fragments held in registers for the whole KV loop (A-operand layout)
  f16x8 qf[2];
  {
    const _Float16* qp = Q + base + (size_t)(q0 + wave * 16 + lr) * 1024 + lq * 8;
    qf[0] = *(const f16x8*)(qp);
    qf[1] = *(const f16x8*)(qp + 32);
  }
  float mrow[4], lsum[4];
  f32x4 o[4] = {};
  for (int r = 0; r < 4; r++) { mrow[r] = -1e30f; lsum[r] = 0.f; }
  const float sc = 0.125f * 1.44269504088896f;  // 1/sqrt(DK) * log2(e)

  const int vr = tid >> 3;         // 0..31 kv row within half-tile
  const int vc = (tid & 7) * 8;    // dk offset

  for (int t = 0; t <= qt; t++) {
    const int kv0 = t * 64;
    // prefetch V tile into regs (overlaps with barrier wait)
    uint4 v0 = *(const uint4*)(V + base + (size_t)(kv0 + vr) * 1024 + vc);
    uint4 v1 = *(const uint4*)(V + base + (size_t)(kv0 + 32 + vr) * 1024 + vc);
    __syncthreads();  // everyone done reading previous Vt
    {
      const _Float16* p0 = (const _Float16*)&v0;
      const _Float16* p1 = (const _Float16*)&v1;
      for (int e = 0; e < 8; e++) {
        Vt[(vc + e) * 72 + vr] = p0[e];
        Vt[(vc + e) * 72 + 32 + vr] = p1[e];
      }
    }
    __syncthreads();

    // S = Q K^T  (K frags straight from global; shared across waves via L1)
    f32x4 s[4];
    for (int n = 0; n < 4; n++) {
      const _Float16* kp =
          K + base + (size_t)(kv0 + n * 16 + lr) * 1024 + lq * 8;
      f16x8 k0 = *(const f16x8*)(kp);
      f16x8 k1 = *(const f16x8*)(kp + 32);
      f32x4 z = {};
      z = __builtin_amdgcn_mfma_f32_16x16x32_f16(qf[0], k0, z, 0, 0, 0);
      z = __builtin_amdgcn_mfma_f32_16x16x32_f16(qf[1], k1, z, 0, 0, 0);
      s[n] = z;
    }
    // scale + causal mask (diagonal tile only)
    const int qrow_base = q0 + wave * 16 + lq * 4;
    for (int n = 0; n < 4; n++) {
      const int col = kv0 + n * 16 + lr;
      for (int r = 0; r < 4; r++) {
        float v = s[n][r] * sc;
        if (t == qt && col > qrow_base + r) v = -1e30f;
        s[n][r] = v;
      }
    }
    // online softmax per row (rows live in 16-lane groups of one quad)
    float alpha[4];
    for (int r = 0; r < 4; r++) {
      float rm = fmaxf(fmaxf(s[0][r], s[1][r]), fmaxf(s[2][r], s[3][r]));
      for (int off = 8; off; off >>= 1) rm = fmaxf(rm, __shfl_xor(rm, off));
      float mnew = fmaxf(mrow[r], rm);
      alpha[r] = exp2f(mrow[r] - mnew);
      mrow[r] = mnew;
      float rs = 0.f;
      for (int n = 0; n < 4; n++) {
        float p = exp2f(s[n][r] - mnew);
        s[n][r] = p;
        rs += p;
      }
      for (int off = 8; off; off >>= 1) rs += __shfl_xor(rs, off);
      lsum[r] = lsum[r] * alpha[r] + rs;
    }
    for (int dn = 0; dn < 4; dn++)
      for (int r = 0; r < 4; r++) o[dn][r] *= alpha[r];

    // P: C-layout -> LDS -> A-operand layout (wave-private strip, no barrier:
    // same-wave LDS ops complete in order)
    _Float16* ps = Ps[wave];
    for (int n = 0; n < 4; n++)
      for (int r = 0; r < 4; r++)
        ps[(lq * 4 + r) * 72 + n * 16 + lr] = (_Float16)s[n][r];
    f16x8 pa0 = *(const f16x8*)(ps + lr * 72 + lq * 8);
    f16x8 pa1 = *(const f16x8*)(ps + lr * 72 + 32 + lq * 8);
    for (int dn = 0; dn < 4; dn++) {
      const _Float16* vp = Vt + (dn * 16 + lr) * 72 + lq * 8;
      f16x8 vf0 = *(const f16x8*)(vp);
      f16x8 vf1 = *(const f16x8*)(vp + 32);
      o[dn] = __builtin_amdgcn_mfma_f32_16x16x32_f16(pa0, vf0, o[dn], 0, 0, 0);
      o[dn] = __builtin_amdgcn_mfma_f32_16x16x32_f16(pa1, vf1, o[dn], 0, 0, 0);
    }
  }

  // epilogue: normalize and store ctx (fp16, [B,S,D] layout)
  for (int r = 0; r < 4; r++) {
    const int row = q0 + wave * 16 + lq * 4 + r;
    const float inv = 1.f / lsum[r];
    for (int dn = 0; dn < 4; dn++)
      ctx[base + (size_t)row * 1024 + dn * 16 + lr] = (_Float16)(o[dn][r] * inv);
  }
}

extern "C" void kernel_launch(void* const* d_in, const int* in_sizes, int n_in,
                              void* d_out, int out_size, void* d_ws,
                              size_t ws_size, hipStream_t stream) {
  const float* x  = (const float*)d_in[0];
  // d_in[1] = causal mask (known analytically, unused)
  const float* Wq = (const float*)d_in[2];
  const float* bq = (const float*)d_in[3];
  const float* Wk = (const float*)d_in[4];
  const float* bk = (const float*)d_in[5];
  const float* Wv = (const float*)d_in[6];
  const float* bv = (const float*)d_in[7];
  const float* Wo = (const float*)d_in[8];
  const float* bo = (const float*)d_in[9];
  float* out = (float*)d_out;

  char* ws = (char*)d_ws;
  const size_t MB = 1 << 20;
  _Float16* xh  = (_Float16*)(ws);             // 8 MB
  _Float16* WqT = (_Float16*)(ws + 8 * MB);    // 2 MB
  _Float16* WkT = (_Float16*)(ws + 10 * MB);
  _Float16* WvT = (_Float16*)(ws + 12 * MB);
  _Float16* WoT = (_Float16*)(ws + 14 * MB);
  _Float16* Qh  = (_Float16*)(ws + 16 * MB);   // 8 MB
  _Float16* Kh  = (_Float16*)(ws + 24 * MB);
  _Float16* Vh  = (_Float16*)(ws + 32 * MB);
  _Float16* ctx = (_Float16*)(ws);             // reuse xh region (xh dead by then)

  cvt_x<<<4096, 256, 0, stream>>>(x, xh);
  wt_kernel<<<dim3(32, 32, 4), 256, 0, stream>>>(Wq, Wk, Wv, Wo, WqT, WkT, WvT,
                                                 WoT);
  gemm_bt<true><<<dim3(32, 8), 256, 0, stream>>>(xh, WqT, bq, Qh, nullptr);
  gemm_bt<true><<<dim3(32, 8), 256, 0, stream>>>(xh, WkT, bk, Kh, nullptr);
  gemm_bt<true><<<dim3(32, 8), 256, 0, stream>>>(xh, WvT, bv, Vh, nullptr);
  attn<<<dim3(32, 16, 2), 256, 0, stream>>>(Qh, Kh, Vh, ctx);
  gemm_bt<false><<<dim3(32, 8), 256, 0, stream>>>(ctx, WoT, bo, nullptr, out);
}

// Round 2
// 268.691 us; speedup vs baseline: 1.3750x; 1.3750x over previous
//
#include <hip/hip_runtime.h>
#include <hip/hip_bf16.h>

// B=2, S=2048, D=1024, H=16, DK=64
// Pipeline (fp16 compute, fp32 accum):
//   1. cvt_x: x fp32 -> fp16
//   2. wt_kernel: W -> W^T fp16 (Wq/Wk/Wv contiguous => fused-GEMM B of 3072 rows)
//   3. gemm_qkv: Q|K|V = x@W + b (Q pre-scaled by 1/sqrt(dk)*log2e), global_load_lds
//   4. vtrans: V [B,S,H,DK] -> VT [B,H,DK,S]  (one-time transpose)
//   5. attn: flash attention, 128 q-rows/block, K+V LDS-staged w/ reg prefetch,
//            ones-column MFMA for the softmax denominator
//   6. gemm_out: out = ctx@Wo + bo -> fp32
// Workspace (40 MiB): xh@0 (later VhT), WqT@8M WkT@10M WvT@12M WoT@14M,
//   Qh@16M, Kh@24M, Vh@32M (later ctx).

typedef _Float16 f16x8 __attribute__((ext_vector_type(8)));
typedef _Float16 f16x4 __attribute__((ext_vector_type(4)));
typedef float f32x4 __attribute__((ext_vector_type(4)));

#define QSCALE 0.180336880111112f  /* 0.125 * log2(e) */

__device__ __forceinline__ void async_copy16(const _Float16* gsrc,
                                             _Float16* ldst) {
  __builtin_amdgcn_global_load_lds(
      (const __attribute__((address_space(1))) void*)gsrc,
      (__attribute__((address_space(3))) void*)ldst, 16, 0, 0);
}

// ---------------- fp32 -> fp16 convert (x) ----------------
__global__ __launch_bounds__(256) void cvt_x(const float* __restrict__ x,
                                             _Float16* __restrict__ xh) {
  int i = (blockIdx.x * 256 + threadIdx.x) * 4;
  float4 v = *(const float4*)(x + i);
  f16x4 o;
  o.x = (_Float16)v.x; o.y = (_Float16)v.y;
  o.z = (_Float16)v.z; o.w = (_Float16)v.w;
  *(f16x4*)(xh + i) = o;
}

// ---------------- W transpose + convert ----------------
__global__ __launch_bounds__(256) void wt_kernel(
    const float* __restrict__ W0, const float* __restrict__ W1,
    const float* __restrict__ W2, const float* __restrict__ W3,
    _Float16* __restrict__ T0, _Float16* __restrict__ T1,
    _Float16* __restrict__ T2, _Float16* __restrict__ T3) {
  const float* W; _Float16* T;
  switch (blockIdx.z) {
    case 0: W = W0; T = T0; break;
    case 1: W = W1; T = T1; break;
    case 2: W = W2; T = T2; break;
    default: W = W3; T = T3; break;
  }
  __shared__ _Float16 tile[32][33];
  const int tx = threadIdx.x & 31, ty = threadIdx.x >> 5;
  const int n0 = blockIdx.x * 32, k0 = blockIdx.y * 32;
  for (int i = 0; i < 4; i++) {
    int kk = k0 + ty + i * 8;
    tile[ty + i * 8][tx] = (_Float16)W[(size_t)kk * 1024 + n0 + tx];
  }
  __syncthreads();
  for (int i = 0; i < 4; i++) {
    int nn = n0 + ty + i * 8;
    T[(size_t)nn * 1024 + k0 + tx] = tile[tx][ty + i * 8];
  }
}

// ---------------- fused QKV GEMM ----------------
// A[4096,1024] @ BtAll[3072,1024]^T + bias -> Qh/Kh/Vh (by n-range), fp16 out.
// 128x128 tile, BK=32, global_load_lds staging (m97 pattern).
__global__ __launch_bounds__(256) void gemm_qkv(
    const _Float16* __restrict__ A, const _Float16* __restrict__ BtAll,
    const float* __restrict__ bq, const float* __restrict__ bk,
    const float* __restrict__ bv, _Float16* __restrict__ Qh,
    _Float16* __restrict__ Kh, _Float16* __restrict__ Vh) {
  __shared__ _Float16 As[128 * 32];
  __shared__ _Float16 Bs[128 * 32];
  const int tid = threadIdx.x;
  const int wave = tid >> 6, lane = tid & 63;
  const int lr = lane & 15, lq = lane >> 4;
  const int m0 = blockIdx.x * 128, n0 = blockIdx.y * 128;
  const int rw = (wave & 1) * 64, cw = (wave >> 1) * 64;

  const int sel = blockIdx.y >> 3;  // 0=Q 1=K 2=V
  const float* bias = sel == 0 ? bq : (sel == 1 ? bk : bv);
  _Float16* out = sel == 0 ? Qh : (sel == 1 ? Kh : Vh);
  const float scl = sel == 0 ? QSCALE : 1.0f;
  const int c0 = n0 & 1023;

  f32x4 acc[4][4] = {};
  // staging: wave w covers rows [w*32, w*32+32); 16 rows per instr
  const int r0 = wave * 32 + (lane >> 2);
  const int woff = (lane & 3) * 8;

  for (int kt = 0; kt < 1024; kt += 32) {
    __syncthreads();
    async_copy16(A + (size_t)(m0 + r0) * 1024 + kt + woff, As + r0 * 32 + woff);
    async_copy16(A + (size_t)(m0 + r0 + 16) * 1024 + kt + woff,
                 As + (r0 + 16) * 32 + woff);
    async_copy16(BtAll + (size_t)(n0 + r0) * 1024 + kt + woff,
                 Bs + r0 * 32 + woff);
    async_copy16(BtAll + (size_t)(n0 + r0 + 16) * 1024 + kt + woff,
                 Bs + (r0 + 16) * 32 + woff);
    __syncthreads();
    f16x8 af[4], bf[4];
    for (int i = 0; i < 4; i++)
      af[i] = *(const f16x8*)(As + (rw + i * 16 + lr) * 32 + lq * 8);
    for (int j = 0; j < 4; j++)
      bf[j] = *(const f16x8*)(Bs + (cw + j * 16 + lr) * 32 + lq * 8);
    for (int i = 0; i < 4; i++)
      for (int j = 0; j < 4; j++)
        acc[i][j] = __builtin_amdgcn_mfma_f32_16x16x32_f16(af[i], bf[j],
                                                           acc[i][j], 0, 0, 0);
  }
  for (int i = 0; i < 4; i++) {
    const int row = m0 + rw + i * 16 + lq * 4;
    for (int j = 0; j < 4; j++) {
      const int col = c0 + cw + j * 16 + lr;
      const float bvl = bias[col];
      for (int r = 0; r < 4; r++)
        out[(size_t)(row + r) * 1024 + col] = (_Float16)((acc[i][j][r] + bvl) * scl);
    }
  }
}

// ---------------- final GEMM: out = ctx @ WoT^T + bo (fp32 out) ----------------
__global__ __launch_bounds__(256) void gemm_out(
    const _Float16* __restrict__ A, const _Float16* __restrict__ Bt,
    const float* __restrict__ bias, float* __restrict__ out) {
  __shared__ _Float16 As[128 * 32];
  __shared__ _Float16 Bs[128 * 32];
  const int tid = threadIdx.x;
  const int wave = tid >> 6, lane = tid & 63;
  const int lr = lane & 15, lq = lane >> 4;
  const int m0 = blockIdx.x * 128, n0 = blockIdx.y * 128;
  const int rw = (wave & 1) * 64, cw = (wave >> 1) * 64;
  f32x4 acc[4][4] = {};
  const int r0 = wave * 32 + (lane >> 2);
  const int woff = (lane & 3) * 8;

  for (int kt = 0; kt < 1024; kt += 32) {
    __syncthreads();
    async_copy16(A + (size_t)(m0 + r0) * 1024 + kt + woff, As + r0 * 32 + woff);
    async_copy16(A + (size_t)(m0 + r0 + 16) * 1024 + kt + woff,
                 As + (r0 + 16) * 32 + woff);
    async_copy16(Bt + (size_t)(n0 + r0) * 1024 + kt + woff,
                 Bs + r0 * 32 + woff);
    async_copy16(Bt + (size_t)(n0 + r0 + 16) * 1024 + kt + woff,
                 Bs + (r0 + 16) * 32 + woff);
    __syncthreads();
    f16x8 af[4], bf[4];
    for (int i = 0; i < 4; i++)
      af[i] = *(const f16x8*)(As + (rw + i * 16 + lr) * 32 + lq * 8);
    for (int j = 0; j < 4; j++)
      bf[j] = *(const f16x8*)(Bs + (cw + j * 16 + lr) * 32 + lq * 8);
    for (int i = 0; i < 4; i++)
      for (int j = 0; j < 4; j++)
        acc[i][j] = __builtin_amdgcn_mfma_f32_16x16x32_f16(af[i], bf[j],
                                                           acc[i][j], 0, 0, 0);
  }
  for (int i = 0; i < 4; i++) {
    const int row = m0 + rw + i * 16 + lq * 4;
    for (int j = 0; j < 4; j++) {
      const int col = n0 + cw + j * 16 + lr;
      const float bvl = bias[col];
      for (int r = 0; r < 4; r++)
        out[(size_t)(row + r) * 1024 + col] = acc[i][j][r] + bvl;
    }
  }
}

// ---------------- V transpose: [B,S,H,DK] -> [B,H,DK,S] ----------------
__global__ __launch_bounds__(256) void vtrans(const _Float16* __restrict__ V,
                                              _Float16* __restrict__ VT) {
  const int s0 = blockIdx.x * 64;  // 32 blocks
  const int bh = blockIdx.y;       // 32 (b*16+h)
  const int b = bh >> 4, h = bh & 15;
  __shared__ _Float16 t[64 * 72];
  const int rr = threadIdx.x >> 3;       // 0..31
  const int c8 = (threadIdx.x & 7) * 8;  // 0..56
  const _Float16* src = V + ((size_t)(b * 2048) + s0) * 1024 + h * 64;
  uint4 v0 = *(const uint4*)(src + (size_t)rr * 1024 + c8);
  uint4 v1 = *(const uint4*)(src + (size_t)(rr + 32) * 1024 + c8);
  const _Float16* p0 = (const _Float16*)&v0;
  const _Float16* p1 = (const _Float16*)&v1;
  for (int e = 0; e < 8; e++) {
    t[(c8 + e) * 72 + rr] = p0[e];
    t[(c8 + e) * 72 + 32 + rr] = p1[e];
  }
  __syncthreads();
  _Float16* dst = VT + ((size_t)bh * 64) * 2048 + s0;
  *(uint4*)(dst + (size_t)rr * 2048 + c8) = *(const uint4*)(t + rr * 72 + c8);
  *(uint4*)(dst + (size_t)(rr + 32) * 2048 + c8) =
      *(const uint4*)(t + (rr + 32) * 72 + c8);
}

// ---------------- flash attention ----------------
// grid (16, H, B): 128 q-rows/block, 4 waves, wave owns rows [w*32, w*32+32).
// K,V staged to LDS with register software-pipeline; ones-column MFMA keeps
// the softmax denominator in an accumulator (no sum shuffle-reduce).
__global__ __launch_bounds__(256) void attn(const _Float16* __restrict__ Q,
                                            const _Float16* __restrict__ K,
                                            const _Float16* __restrict__ VT,
                                            _Float16* __restrict__ ctx) {
  const int qt = gridDim.x - 1 - blockIdx.x;  // longest blocks first
  const int h = blockIdx.y, b = blockIdx.z;
  const int tid = threadIdx.x, wave = tid >> 6, lane = tid & 63;
  const int lr = lane & 15, lq = lane >> 4;
  const int q0 = qt * 128;
  const size_t qkbase = ((size_t)b * 2048) * 1024 + h * 64;
  const size_t vtbase = ((size_t)(b * 16 + h)) * 64 * 2048;

  __shared__ _Float16 Ks[64 * 72];
  __shared__ _Float16 Vt[64 * 72];
  __shared__ _Float16 Ps[4][32 * 72];

  // Q fragments (pre-scaled in gemm_qkv): 2 m-tiles
  f16x8 qf[2][2];
  for (int m = 0; m < 2; m++) {
    const _Float16* qp =
        Q + qkbase + (size_t)(q0 + wave * 32 + m * 16 + lr) * 1024 + lq * 8;
    qf[m][0] = *(const f16x8*)qp;
    qf[m][1] = *(const f16x8*)(qp + 32);
  }
  f16x8 onesf;
  {
    _Float16 ov = (lr == 0) ? (_Float16)1.0f : (_Float16)0.0f;
    for (int i = 0; i < 8; i++) onesf[i] = ov;
  }
  float mrow[2][4];
  f32x4 o[2][4] = {};
  f32x4 ol[2] = {};
  for (int m = 0; m < 2; m++)
    for (int r = 0; r < 4; r++) mrow[m][r] = -1e30f;

  // staging pattern: row = tid>>2 (0..63), two 16B chunks at col (tid&3)*8, +32
  const int sgr = tid >> 2, sgc = (tid & 3) * 8;
  const _Float16* Kg = K + qkbase + (size_t)sgr * 1024 + sgc;
  const _Float16* Vg = VT + vtbase + (size_t)sgr * 2048 + sgc;
  uint4 ka = *(const uint4*)Kg, kb = *(const uint4*)(Kg + 32);
  uint4 va = *(const uint4*)Vg, vb = *(const uint4*)(Vg + 32);

  const int tmax = 2 * qt + 1;
  for (int t = 0;; t++) {
    if (t) __syncthreads();  // readers done with previous tile
    *(uint4*)(Ks + sgr * 72 + sgc) = ka;
    *(uint4*)(Ks + sgr * 72 + sgc + 32) = kb;
    *(uint4*)(Vt + sgr * 72 + sgc) = va;
    *(uint4*)(Vt + sgr * 72 + sgc + 32) = vb;
    if (t < tmax) {  // prefetch next tile; in flight during compute
      const _Float16* kg = Kg + (size_t)(t + 1) * 64 * 1024;
      const _Float16* vg = Vg + (t + 1) * 64;
      ka = *(const uint4*)kg; kb = *(const uint4*)(kg + 32);
      va = *(const uint4*)vg; vb = *(const uint4*)(vg + 32);
    }
    __syncthreads();

    const int kv0 = t * 64;
    // S = Q K^T
    f32x4 s[2][4];
    for (int n = 0; n < 4; n++) {
      f16x8 k0 = *(const f16x8*)(Ks + (n * 16 + lr) * 72 + lq * 8);
      f16x8 k1 = *(const f16x8*)(Ks + (n * 16 + lr) * 72 + 32 + lq * 8);
      for (int m = 0; m < 2; m++) {
        f32x4 z = {};
        z = __builtin_amdgcn_mfma_f32_16x16x32_f16(qf[m][0], k0, z, 0, 0, 0);
        z = __builtin_amdgcn_mfma_f32_16x16x32_f16(qf[m][1], k1, z, 0, 0, 0);
        s[m][n] = z;
      }
    }
    if (t >= 2 * qt) {  // causal mask: only the two diagonal tiles
      for (int m = 0; m < 2; m++) {
        const int rowb = q0 + wave * 32 + m * 16 + lq * 4;
        for (int n = 0; n < 4; n++) {
          const int col = kv0 + n * 16 + lr;
          for (int r = 0; r < 4; r++)
            if (col > rowb + r) s[m][n][r] = -1e30f;
        }
      }
    }
    // online softmax (scores already in log2 units); denominator via ones-MFMA
    for (int m = 0; m < 2; m++) {
      float alpha[4];
      for (int r = 0; r < 4; r++) {
        float rm = fmaxf(fmaxf(s[m][0][r], s[m][1][r]),
                         fmaxf(s[m][2][r], s[m][3][r]));
        rm = fmaxf(rm, __shfl_xor(rm, 1));
        rm = fmaxf(rm, __shfl_xor(rm, 2));
        rm = fmaxf(rm, __shfl_xor(rm, 4));
        rm = fmaxf(rm, __shfl_xor(rm, 8));
        float mnew = fmaxf(mrow[m][r], rm);
        alpha[r] = exp2f(mrow[m][r] - mnew);
        mrow[m][r] = mnew;
        for (int n = 0; n < 4; n++) s[m][n][r] = exp2f(s[m][n][r] - mnew);
      }
      _Float16* ps = Ps[wave] + m * 16 * 72;
      for (int n = 0; n < 4; n++)
        for (int r = 0; r < 4; r++)
          ps[(lq * 4 + r) * 72 + n * 16 + lr] = (_Float16)s[m][n][r];
      for (int dn = 0; dn < 4; dn++)
        for (int r = 0; r < 4; r++) o[m][dn][r] *= alpha[r];
      for (int r = 0; r < 4; r++) ol[m][r] *= alpha[r];
    }
    // O += P V  (P via wave-private LDS strip; same-wave ops are in-order)
    f16x8 vf0[4], vf1[4];
    for (int dn = 0; dn < 4; dn++) {
      vf0[dn] = *(const f16x8*)(Vt + (dn * 16 + lr) * 72 + lq * 8);
      vf1[dn] = *(const f16x8*)(Vt + (dn * 16 + lr) * 72 + 32 + lq * 8);
    }
    for (int m = 0; m < 2; m++) {
      const _Float16* ps = Ps[wave] + m * 16 * 72;
      f16x8 pa0 = *(const f16x8*)(ps + lr * 72 + lq * 8);
      f16x8 pa1 = *(const f16x8*)(ps + lr * 72 + 32 + lq * 8);
      for (int dn = 0; dn < 4; dn++) {
        o[m][dn] = __builtin_amdgcn_mfma_f32_16x16x32_f16(pa0, vf0[dn],
                                                          o[m][dn], 0, 0, 0);
        o[m][dn] = __builtin_amdgcn_mfma_f32_16x16x32_f16(pa1, vf1[dn],
                                                          o[m][dn], 0, 0, 0);
      }
      ol[m] = __builtin_amdgcn_mfma_f32_16x16x32_f16(pa0, onesf, ol[m], 0, 0, 0);
      ol[m] = __builtin_amdgcn_mfma_f32_16x16x32_f16(pa1, onesf, ol[m], 0, 0, 0);
    }
    if (t == tmax) break;
  }

  // epilogue: broadcast denominator (col 0 of ol lives in lane lq*16), store
  for (int m = 0; m < 2; m++) {
    for (int r = 0; r < 4; r++) {
      float l = __shfl(ol[m][r], lane & 48);
      float inv = 1.0f / l;
      const int row = q0 + wave * 32 + m * 16 + lq * 4 + r;
      for (int dn = 0; dn < 4; dn++)
        ctx[qkbase + (size_t)row * 1024 + dn * 16 + lr] =
            (_Float16)(o[m][dn][r] * inv);
    }
  }
}

extern "C" void kernel_launch(void* const* d_in, const int* in_sizes, int n_in,
                              void* d_out, int out_size, void* d_ws,
                              size_t ws_size, hipStream_t stream) {
  const float* x  = (const float*)d_in[0];
  const float* Wq = (const float*)d_in[2];
  const float* bq = (const float*)d_in[3];
  const float* Wk = (const float*)d_in[4];
  const float* bk = (const float*)d_in[5];
  const float* Wv = (const float*)d_in[6];
  const float* bv = (const float*)d_in[7];
  const float* Wo = (const float*)d_in[8];
  const float* bo = (const float*)d_in[9];
  float* out = (float*)d_out;

  char* ws = (char*)d_ws;
  const size_t MB = 1 << 20;
  _Float16* xh  = (_Float16*)(ws);            // 8 MB; dead after gemm_qkv
  _Float16* WTs = (_Float16*)(ws + 8 * MB);   // WqT|WkT|WvT contiguous (6 MB)
  _Float16* WqT = WTs;
  _Float16* WkT = (_Float16*)(ws + 10 * MB);
  _Float16* WvT = (_Float16*)(ws + 12 * MB);
  _Float16* WoT = (_Float16*)(ws + 14 * MB);
  _Float16* Qh  = (_Float16*)(ws + 16 * MB);
  _Float16* Kh  = (_Float16*)(ws + 24 * MB);
  _Float16* Vh  = (_Float16*)(ws + 32 * MB);  // dead after vtrans
  _Float16* VhT = (_Float16*)(ws);            // over xh
  _Float16* ctx = (_Float16*)(ws + 32 * MB);  // over Vh

  cvt_x<<<4096, 256, 0, stream>>>(x, xh);
  wt_kernel<<<dim3(32, 32, 4), 256, 0, stream>>>(Wq, Wk, Wv, Wo, WqT, WkT, WvT,
                                                 WoT);
  gemm_qkv<<<dim3(32, 24), 256, 0, stream>>>(xh, WTs, bq, bk, bv, Qh, Kh, Vh);
  vtrans<<<dim3(32, 32), 256, 0, stream>>>(Vh, VhT);
  attn<<<dim3(16, 16, 2), 256, 0, stream>>>(Qh, Kh, VhT, ctx);
  gemm_out<<<dim3(32, 8), 256, 0, stream>>>(ctx, WoT, bo, out);
}

// Round 3
// 210.512 us; speedup vs baseline: 1.7550x; 1.2764x over previous
//
#include <hip/hip_runtime.h>
#include <hip/hip_bf16.h>

// B=2, S=2048, D=1024, H=16, DK=64
// Pipeline (fp16 compute, fp32 accum):
//   1. cvt_x: x fp32 -> fp16
//   2. wt_kernel: W -> W^T fp16 (Wq/Wk/Wv contiguous => fused-GEMM B of 3072 rows)
//   3. gemm_qkv: Q|K|V = x@W + b; Q pre-scaled by 1/sqrt(dk)*log2e;
//      V written TRANSPOSED to VT [B,H,DK,S] in the epilogue (8B packed stores)
//   4. attn: flash attention. S^T = K.Q^T operand-swap so P exits QK^T already
//      in mfma_16x16x16 A-layout (no LDS round trip). K/V double-buffered LDS,
//      prefetch issued AFTER the barrier. Blocks pair q-tiles (j, 31-j):
//      exactly 33 kv-iters per block.
//   5. gemm_out: out = ctx@Wo + bo -> fp32
// Workspace (40 MiB): xh@0 (later ctx), WqT@8M WkT@10M WvT@12M WoT@14M,
//   Qh@16M, Kh@24M, VT@32M (8 MB).

typedef _Float16 f16x8 __attribute__((ext_vector_type(8)));
typedef _Float16 f16x4 __attribute__((ext_vector_type(4)));
typedef float f32x4 __attribute__((ext_vector_type(4)));

#define QSCALE 0.180336880111112f /* 0.125 * log2(e) */

__device__ __forceinline__ void async_copy16(const _Float16* gsrc,
                                             _Float16* ldst) {
  __builtin_amdgcn_global_load_lds(
      (const __attribute__((address_space(1))) void*)gsrc,
      (__attribute__((address_space(3))) void*)ldst, 16, 0, 0);
}

// ---------------- fp32 -> fp16 convert (x) ----------------
__global__ __launch_bounds__(256) void cvt_x(const float* __restrict__ x,
                                             _Float16* __restrict__ xh) {
  int i = (blockIdx.x * 256 + threadIdx.x) * 4;
  float4 v = *(const float4*)(x + i);
  f16x4 o;
  o.x = (_Float16)v.x; o.y = (_Float16)v.y;
  o.z = (_Float16)v.z; o.w = (_Float16)v.w;
  *(f16x4*)(xh + i) = o;
}

// ---------------- W transpose + convert ----------------
__global__ __launch_bounds__(256) void wt_kernel(
    const float* __restrict__ W0, const float* __restrict__ W1,
    const float* __restrict__ W2, const float* __restrict__ W3,
    _Float16* __restrict__ T0, _Float16* __restrict__ T1,
    _Float16* __restrict__ T2, _Float16* __restrict__ T3) {
  const float* W; _Float16* T;
  switch (blockIdx.z) {
    case 0: W = W0; T = T0; break;
    case 1: W = W1; T = T1; break;
    case 2: W = W2; T = T2; break;
    default: W = W3; T = T3; break;
  }
  __shared__ _Float16 tile[32][33];
  const int tx = threadIdx.x & 31, ty = threadIdx.x >> 5;
  const int n0 = blockIdx.x * 32, k0 = blockIdx.y * 32;
  for (int i = 0; i < 4; i++) {
    int kk = k0 + ty + i * 8;
    tile[ty + i * 8][tx] = (_Float16)W[(size_t)kk * 1024 + n0 + tx];
  }
  __syncthreads();
  for (int i = 0; i < 4; i++) {
    int nn = n0 + ty + i * 8;
    T[(size_t)nn * 1024 + k0 + tx] = tile[tx][ty + i * 8];
  }
}

// ---------------- fused QKV GEMM ----------------
// A[4096,1024] @ BtAll[3072,1024]^T + bias. Q,K -> [B,S,D] fp16;
// V -> VT [B,H,DK,S] (transposed in epilogue, f16x4 packed stores).
__global__ __launch_bounds__(256) void gemm_qkv(
    const _Float16* __restrict__ A, const _Float16* __restrict__ BtAll,
    const float* __restrict__ bq, const float* __restrict__ bk,
    const float* __restrict__ bv, _Float16* __restrict__ Qh,
    _Float16* __restrict__ Kh, _Float16* __restrict__ VT) {
  __shared__ _Float16 As[128 * 32];
  __shared__ _Float16 Bs[128 * 32];
  const int tid = threadIdx.x;
  const int wave = tid >> 6, lane = tid & 63;
  const int lr = lane & 15, lq = lane >> 4;
  const int m0 = blockIdx.x * 128, n0 = blockIdx.y * 128;
  const int rw = (wave & 1) * 64, cw = (wave >> 1) * 64;

  const int sel = blockIdx.y >> 3;  // 0=Q 1=K 2=V
  const float* bias = sel == 0 ? bq : (sel == 1 ? bk : bv);
  const int c0 = n0 & 1023;

  f32x4 acc[4][4] = {};
  const int r0 = wave * 32 + (lane >> 2);
  const int woff = (lane & 3) * 8;

  for (int kt = 0; kt < 1024; kt += 32) {
    __syncthreads();
    async_copy16(A + (size_t)(m0 + r0) * 1024 + kt + woff, As + r0 * 32 + woff);
    async_copy16(A + (size_t)(m0 + r0 + 16) * 1024 + kt + woff,
                 As + (r0 + 16) * 32 + woff);
    async_copy16(BtAll + (size_t)(n0 + r0) * 1024 + kt + woff,
                 Bs + r0 * 32 + woff);
    async_copy16(BtAll + (size_t)(n0 + r0 + 16) * 1024 + kt + woff,
                 Bs + (r0 + 16) * 32 + woff);
    __syncthreads();
    f16x8 af[4], bf[4];
    for (int i = 0; i < 4; i++)
      af[i] = *(const f16x8*)(As + (rw + i * 16 + lr) * 32 + lq * 8);
    for (int j = 0; j < 4; j++)
      bf[j] = *(const f16x8*)(Bs + (cw + j * 16 + lr) * 32 + lq * 8);
    for (int i = 0; i < 4; i++)
      for (int j = 0; j < 4; j++)
        acc[i][j] = __builtin_amdgcn_mfma_f32_16x16x32_f16(af[i], bf[j],
                                                           acc[i][j], 0, 0, 0);
  }

  if (sel == 2) {  // V: write transposed [B,H,DK,S]
    for (int i = 0; i < 4; i++) {
      const int row = m0 + rw + i * 16 + lq * 4;  // s-index (global)
      const int bb = row >> 11, ss = row & 2047;
      for (int j = 0; j < 4; j++) {
        const int col = c0 + cw + j * 16 + lr;  // d-index
        const int hh = col >> 6, dk = col & 63;
        const float bvl = bias[col];
        f16x4 pv;
        for (int r = 0; r < 4; r++) pv[r] = (_Float16)(acc[i][j][r] + bvl);
        *(f16x4*)(VT + ((size_t)(bb * 16 + hh) * 64 + dk) * 2048 + ss) = pv;
      }
    }
  } else {
    _Float16* out = sel == 0 ? Qh : Kh;
    const float scl = sel == 0 ? QSCALE : 1.0f;
    for (int i = 0; i < 4; i++) {
      const int row = m0 + rw + i * 16 + lq * 4;
      for (int j = 0; j < 4; j++) {
        const int col = c0 + cw + j * 16 + lr;
        const float bvl = bias[col];
        for (int r = 0; r < 4; r++)
          out[(size_t)(row + r) * 1024 + col] =
              (_Float16)((acc[i][j][r] + bvl) * scl);
      }
    }
  }
}

// ---------------- final GEMM: out = ctx @ WoT^T + bo (fp32 out) ----------------
__global__ __launch_bounds__(256) void gemm_out(
    const _Float16* __restrict__ A, const _Float16* __restrict__ Bt,
    const float* __restrict__ bias, float* __restrict__ out) {
  __shared__ _Float16 As[128 * 32];
  __shared__ _Float16 Bs[128 * 32];
  const int tid = threadIdx.x;
  const int wave = tid >> 6, lane = tid & 63;
  const int lr = lane & 15, lq = lane >> 4;
  const int m0 = blockIdx.x * 128, n0 = blockIdx.y * 128;
  const int rw = (wave & 1) * 64, cw = (wave >> 1) * 64;
  f32x4 acc[4][4] = {};
  const int r0 = wave * 32 + (lane >> 2);
  const int woff = (lane & 3) * 8;

  for (int kt = 0; kt < 1024; kt += 32) {
    __syncthreads();
    async_copy16(A + (size_t)(m0 + r0) * 1024 + kt + woff, As + r0 * 32 + woff);
    async_copy16(A + (size_t)(m0 + r0 + 16) * 1024 + kt + woff,
                 As + (r0 + 16) * 32 + woff);
    async_copy16(Bt + (size_t)(n0 + r0) * 1024 + kt + woff,
                 Bs + r0 * 32 + woff);
    async_copy16(Bt + (size_t)(n0 + r0 + 16) * 1024 + kt + woff,
                 Bs + (r0 + 16) * 32 + woff);
    __syncthreads();
    f16x8 af[4], bf[4];
    for (int i = 0; i < 4; i++)
      af[i] = *(const f16x8*)(As + (rw + i * 16 + lr) * 32 + lq * 8);
    for (int j = 0; j < 4; j++)
      bf[j] = *(const f16x8*)(Bs + (cw + j * 16 + lr) * 32 + lq * 8);
    for (int i = 0; i < 4; i++)
      for (int j = 0; j < 4; j++)
        acc[i][j] = __builtin_amdgcn_mfma_f32_16x16x32_f16(af[i], bf[j],
                                                           acc[i][j], 0, 0, 0);
  }
  for (int i = 0; i < 4; i++) {
    const int row = m0 + rw + i * 16 + lq * 4;
    for (int j = 0; j < 4; j++) {
      const int col = n0 + cw + j * 16 + lr;
      const float bvl = bias[col];
      for (int r = 0; r < 4; r++)
        out[(size_t)(row + r) * 1024 + col] = acc[i][j][r] + bvl;
    }
  }
}

// ---------------- flash attention (operand-swap, no P round trip) ----------
// grid (16, H, B): block processes q-tiles j and 31-j (64 rows each) => every
// block does exactly 33 kv-tile iterations. 4 waves; wave owns 16 q rows.
// S^T = K.Q^T: per lane S[q=lane&15][kv=lq*4+r] == A-layout of 16x16x16 MFMA.
// K/V double-buffered in LDS; prefetch issued after the barrier.
__global__ __launch_bounds__(256) void attn(const _Float16* __restrict__ Q,
                                            const _Float16* __restrict__ K,
                                            const _Float16* __restrict__ VT,
                                            _Float16* __restrict__ ctx) {
  const int j = blockIdx.x;
  const int h = blockIdx.y, b = blockIdx.z;
  const int tid = threadIdx.x, wave = tid >> 6, lane = tid & 63;
  const int lr = lane & 15, lq = lane >> 4;
  const size_t qkbase = ((size_t)b * 2048) * 1024 + h * 64;
  const size_t vtbase = ((size_t)(b * 16 + h)) * 64 * 2048;

  __shared__ _Float16 Ks[2][64 * 72];
  __shared__ _Float16 Vs[2][64 * 72];

  const int sgr = tid >> 2, sgc = (tid & 3) * 8;
  const _Float16* Kg0 = K + qkbase + (size_t)sgr * 1024 + sgc;
  const _Float16* Vg0 = VT + vtbase + (size_t)sgr * 2048 + sgc;

  for (int phase = 0; phase < 2; phase++) {
    const int qt = phase ? (31 - j) : j;
    const int q0 = qt * 64;
    // Q fragments (pre-scaled by QSCALE in gemm_qkv); q = lane&15
    const _Float16* qp =
        Q + qkbase + (size_t)(q0 + wave * 16 + lr) * 1024 + lq * 8;
    f16x8 qf0 = *(const f16x8*)qp;
    f16x8 qf1 = *(const f16x8*)(qp + 32);

    float mrow = -1e30f, lsum = 0.f;
    f32x4 o[4] = {};

    // preload tile 0
    uint4 ka = *(const uint4*)Kg0, kb = *(const uint4*)(Kg0 + 32);
    uint4 va = *(const uint4*)Vg0, vb = *(const uint4*)(Vg0 + 32);
    __syncthreads();  // buffer reuse across phases

    for (int t = 0; t <= qt; t++) {
      _Float16* ksb = Ks[t & 1];
      _Float16* vsb = Vs[t & 1];
      *(uint4*)(ksb + sgr * 72 + sgc) = ka;
      *(uint4*)(ksb + sgr * 72 + sgc + 32) = kb;
      *(uint4*)(vsb + sgr * 72 + sgc) = va;
      *(uint4*)(vsb + sgr * 72 + sgc + 32) = vb;
      __syncthreads();
      if (t < qt) {  // prefetch AFTER barrier: flies during compute of tile t
        const _Float16* kg = Kg0 + (size_t)(t + 1) * 64 * 1024;
        const _Float16* vg = Vg0 + (t + 1) * 64;
        ka = *(const uint4*)kg; kb = *(const uint4*)(kg + 32);
        va = *(const uint4*)vg; vb = *(const uint4*)(vg + 32);
      }

      // S^T = K.Q^T : per lane s[ks][r] = S[q=lane&15][kv=ks*16+lq*4+r]
      f32x4 s[4];
      for (int ks = 0; ks < 4; ks++) {
        f16x8 k0 = *(const f16x8*)(ksb + (ks * 16 + lr) * 72 + lq * 8);
        f16x8 k1 = *(const f16x8*)(ksb + (ks * 16 + lr) * 72 + 32 + lq * 8);
        f32x4 z = {};
        z = __builtin_amdgcn_mfma_f32_16x16x32_f16(k0, qf0, z, 0, 0, 0);
        z = __builtin_amdgcn_mfma_f32_16x16x32_f16(k1, qf1, z, 0, 0, 0);
        s[ks] = z;
      }
      if (t == qt) {  // causal mask, diagonal tile only
        const int qcol = q0 + wave * 16 + lr;
        const int kv0 = t * 64;
        for (int ks = 0; ks < 4; ks++)
          for (int r = 0; r < 4; r++)
            if (kv0 + ks * 16 + lq * 4 + r > qcol) s[ks][r] = -1e30f;
      }
      // online softmax: row state lives per-lane (q = lane&15)
      float mx = s[0][0];
      for (int ks = 0; ks < 4; ks++)
        for (int r = 0; r < 4; r++) mx = fmaxf(mx, s[ks][r]);
      mx = fmaxf(mx, __shfl_xor(mx, 16));
      mx = fmaxf(mx, __shfl_xor(mx, 32));
      float mnew = fmaxf(mrow, mx);
      float alpha = exp2f(mrow - mnew);
      mrow = mnew;
      float rs = 0.f;
      f16x4 pa[4];
      for (int ks = 0; ks < 4; ks++)
        for (int r = 0; r < 4; r++) {
          float p = exp2f(s[ks][r] - mnew);
          rs += p;
          pa[ks][r] = (_Float16)p;
        }
      rs += __shfl_xor(rs, 16);
      rs += __shfl_xor(rs, 32);
      lsum = lsum * alpha + rs;
      // rescale O (rows q = lq*4+r need alpha from lane q)
      float ar[4];
      for (int r = 0; r < 4; r++) ar[r] = __shfl(alpha, lq * 4 + r);
      for (int dn = 0; dn < 4; dn++)
        for (int r = 0; r < 4; r++) o[dn][r] *= ar[r];
      // O += P.V  (P already in A-layout of 16x16x16)
      for (int ks = 0; ks < 4; ks++)
        for (int dn = 0; dn < 4; dn++) {
          f16x4 vf = *(const f16x4*)(vsb + (dn * 16 + lr) * 72 + ks * 16 + lq * 4);
          o[dn] =
              __builtin_amdgcn_mfma_f32_16x16x16f16(pa[ks], vf, o[dn], 0, 0, 0);
        }
    }

    // epilogue: O rows q = lq*4+r, cols d = dn*16+lr
    for (int r = 0; r < 4; r++) {
      float lv = __shfl(lsum, lq * 4 + r);
      float inv = 1.0f / lv;
      const int row = q0 + wave * 16 + lq * 4 + r;
      for (int dn = 0; dn < 4; dn++)
        ctx[qkbase + (size_t)row * 1024 + dn * 16 + lr] =
            (_Float16)(o[dn][r] * inv);
    }
  }
}

extern "C" void kernel_launch(void* const* d_in, const int* in_sizes, int n_in,
                              void* d_out, int out_size, void* d_ws,
                              size_t ws_size, hipStream_t stream) {
  const float* x  = (const float*)d_in[0];
  const float* Wq = (const float*)d_in[2];
  const float* bq = (const float*)d_in[3];
  const float* Wk = (const float*)d_in[4];
  const float* bk = (const float*)d_in[5];
  const float* Wv = (const float*)d_in[6];
  const float* bv = (const float*)d_in[7];
  const float* Wo = (const float*)d_in[8];
  const float* bo = (const float*)d_in[9];
  float* out = (float*)d_out;

  char* ws = (char*)d_ws;
  const size_t MB = 1 << 20;
  _Float16* xh  = (_Float16*)(ws);            // 8 MB; dead after gemm_qkv
  _Float16* WTs = (_Float16*)(ws + 8 * MB);   // WqT|WkT|WvT contiguous (6 MB)
  _Float16* WqT = WTs;
  _Float16* WkT = (_Float16*)(ws + 10 * MB);
  _Float16* WvT = (_Float16*)(ws + 12 * MB);
  _Float16* WoT = (_Float16*)(ws + 14 * MB);
  _Float16* Qh  = (_Float16*)(ws + 16 * MB);
  _Float16* Kh  = (_Float16*)(ws + 24 * MB);
  _Float16* VT  = (_Float16*)(ws + 32 * MB);  // 8 MB [B,H,DK,S]
  _Float16* ctx = (_Float16*)(ws);            // over xh

  cvt_x<<<4096, 256, 0, stream>>>(x, xh);
  wt_kernel<<<dim3(32, 32, 4), 256, 0, stream>>>(Wq, Wk, Wv, Wo, WqT, WkT, WvT,
                                                 WoT);
  gemm_qkv<<<dim3(32, 24), 256, 0, stream>>>(xh, WTs, bq, bk, bv, Qh, Kh, VT);
  attn<<<dim3(16, 16, 2), 256, 0, stream>>>(Qh, Kh, VT, ctx);
  gemm_out<<<dim3(32, 8), 256, 0, stream>>>(ctx, WoT, bo, out);
}